// Round 1
// 1013.444 us; speedup vs baseline: 1.0149x; 1.0149x over previous
//
#include <hip/hip_runtime.h>
#include <hip/hip_bf16.h>

// Shapes: B=16, Q=1, KV=8192, D=1024, all fp32.
// out[b,d] = softmax(q_b . K_b / 32) @ V_b  with q/new_k/new_v = x @ W^T appended.

#define B_SZ 16
#define KV_SZ 8192
#define D_SZ 1024
#define CHUNK 128
#define NCH 64          // KV_SZ / CHUNK
#define PPB 64          // partials per batch: new-token row folded into chunk 63

// ---------------- Kernel 1: fused QKV projection ----------------
// One wave per (matrix, e): reads weight row once, computes all 16 batches.
// x (16x1024 = 64 KB) staged in LDS.
__global__ __launch_bounds__(256) void proj_kernel(
    const float* __restrict__ x,
    const float* __restrict__ wq, const float* __restrict__ wk, const float* __restrict__ wv,
    float* __restrict__ q_ws, float* __restrict__ nk_ws, float* __restrict__ nv_ws)
{
    __shared__ float xs[B_SZ * D_SZ];   // 64 KB
    const int tid = threadIdx.x;
    const float4* x4 = (const float4*)x;
    float4* xs4 = (float4*)xs;
    for (int i = tid; i < (B_SZ * D_SZ) / 4; i += 256) xs4[i] = x4[i];
    __syncthreads();

    const int wave = tid >> 6, lane = tid & 63;
    const int row = blockIdx.x * 4 + wave;   // 0..3071
    const int mat = row >> 10;
    const int e   = row & 1023;
    const float* W   = (mat == 0) ? wq   : (mat == 1 ? wk    : wv);
    float*       out = (mat == 0) ? q_ws : (mat == 1 ? nk_ws : nv_ws);

    float4 w4[4];
#pragma unroll
    for (int j = 0; j < 4; ++j)
        w4[j] = *(const float4*)(W + (size_t)e * D_SZ + j * 256 + lane * 4);

    float acc[B_SZ];
#pragma unroll
    for (int b = 0; b < B_SZ; ++b) acc[b] = 0.f;
#pragma unroll
    for (int b = 0; b < B_SZ; ++b) {
#pragma unroll
        for (int j = 0; j < 4; ++j) {
            float4 xv = *(const float4*)(xs + b * D_SZ + j * 256 + lane * 4);
            acc[b] += w4[j].x * xv.x + w4[j].y * xv.y + w4[j].z * xv.z + w4[j].w * xv.w;
        }
    }
#pragma unroll
    for (int b = 0; b < B_SZ; ++b) {
        float s = acc[b];
#pragma unroll
        for (int off = 32; off > 0; off >>= 1) s += __shfl_xor(s, off, 64);
        if (lane == 0) out[b * D_SZ + e] = s;
    }
}

// ---------------- Kernel 2: flash-decode partials ----------------
// Block = (batch, chunk). 4 waves, each wave streams strided rows of the chunk
// with online softmax; LDS combine -> one (M, L, o[1024]) partial per block.
// Inner loop is branchless with affine pointer increments so the compiler can
// software-pipeline the 8 global_load_dwordx4 across rows. The new-token row
// (q.nk / nv) is handled once, after the loop, by wave 0 of chunk 63.
__global__ __launch_bounds__(256) void attn_partial_kernel(
    const float* __restrict__ cache_k, const float* __restrict__ cache_v,
    const float* __restrict__ q_ws, const float* __restrict__ nk_ws, const float* __restrict__ nv_ws,
    float* __restrict__ m_ws, float* __restrict__ l_ws, float* __restrict__ o_ws)
{
    const int blk = blockIdx.x;
    const int b = blk >> 6;        // / PPB
    const int c = blk & 63;        // % PPB
    const int tid = threadIdx.x, wave = tid >> 6, lane = tid & 63;

    // q fragment in registers: lane covers d = j*256 + lane*4 .. +3
    float4 q4[4];
#pragma unroll
    for (int j = 0; j < 4; ++j)
        q4[j] = *(const float4*)(q_ws + b * D_SZ + j * 256 + lane * 4);

    float m = -3.0e38f, l = 0.f;
    float4 o4[4];
#pragma unroll
    for (int j = 0; j < 4; ++j) { o4[j].x = 0.f; o4[j].y = 0.f; o4[j].z = 0.f; o4[j].w = 0.f; }

    // Affine base: row (c*CHUNK + wave + 4*i), this lane's 16B slice.
    const size_t base0 = ((size_t)b * KV_SZ + (size_t)c * CHUNK + wave) * D_SZ + lane * 4;
    const float* Kp = cache_k + base0;
    const float* Vp = cache_v + base0;

    for (int i = 0; i < CHUNK / 4; ++i, Kp += 4 * D_SZ, Vp += 4 * D_SZ) {
        float4 k4[4], v4[4];
#pragma unroll
        for (int j = 0; j < 4; ++j) k4[j] = *(const float4*)(Kp + j * 256);
#pragma unroll
        for (int j = 0; j < 4; ++j) v4[j] = *(const float4*)(Vp + j * 256);

        float s = 0.f;
#pragma unroll
        for (int j = 0; j < 4; ++j)
            s += q4[j].x * k4[j].x + q4[j].y * k4[j].y + q4[j].z * k4[j].z + q4[j].w * k4[j].w;
#pragma unroll
        for (int off = 32; off > 0; off >>= 1) s += __shfl_xor(s, off, 64);
        s *= 0.03125f;   // 1/sqrt(1024)

        // Defer-max: when s <= m, alpha = exp(0) = 1 exactly -> skip the rescale.
        if (s > m) {                       // wave-uniform branch (s uniform after reduce)
            const float alpha = __expf(m - s);
            l *= alpha;
#pragma unroll
            for (int j = 0; j < 4; ++j) {
                o4[j].x *= alpha; o4[j].y *= alpha; o4[j].z *= alpha; o4[j].w *= alpha;
            }
            m = s;
        }
        const float p = __expf(s - m);
        l += p;
#pragma unroll
        for (int j = 0; j < 4; ++j) {
            o4[j].x += p * v4[j].x;
            o4[j].y += p * v4[j].y;
            o4[j].z += p * v4[j].z;
            o4[j].w += p * v4[j].w;
        }
    }

    // New-token row: once per batch, by wave 0 of the last chunk.
    if (c == NCH - 1 && wave == 0) {
        float4 k4[4], v4[4];
#pragma unroll
        for (int j = 0; j < 4; ++j) k4[j] = *(const float4*)(nk_ws + b * D_SZ + j * 256 + lane * 4);
#pragma unroll
        for (int j = 0; j < 4; ++j) v4[j] = *(const float4*)(nv_ws + b * D_SZ + j * 256 + lane * 4);
        float s = 0.f;
#pragma unroll
        for (int j = 0; j < 4; ++j)
            s += q4[j].x * k4[j].x + q4[j].y * k4[j].y + q4[j].z * k4[j].z + q4[j].w * k4[j].w;
#pragma unroll
        for (int off = 32; off > 0; off >>= 1) s += __shfl_xor(s, off, 64);
        s *= 0.03125f;
        if (s > m) {
            const float alpha = __expf(m - s);
            l *= alpha;
#pragma unroll
            for (int j = 0; j < 4; ++j) {
                o4[j].x *= alpha; o4[j].y *= alpha; o4[j].z *= alpha; o4[j].w *= alpha;
            }
            m = s;
        }
        const float p = __expf(s - m);
        l += p;
#pragma unroll
        for (int j = 0; j < 4; ++j) {
            o4[j].x += p * v4[j].x;
            o4[j].y += p * v4[j].y;
            o4[j].z += p * v4[j].z;
            o4[j].w += p * v4[j].w;
        }
    }

    // Combine the 4 waves' online-softmax states.
    __shared__ float sm[4], sl[4];
    __shared__ float so[4 * D_SZ];   // 16 KB
    if (lane == 0) { sm[wave] = m; sl[wave] = l; }
    __syncthreads();
    const float M = fmaxf(fmaxf(sm[0], sm[1]), fmaxf(sm[2], sm[3]));
    const float L = sl[0] * __expf(sm[0] - M) + sl[1] * __expf(sm[1] - M) +
                    sl[2] * __expf(sm[2] - M) + sl[3] * __expf(sm[3] - M);
    const float factor = __expf(m - M);   // this wave's rescale
#pragma unroll
    for (int j = 0; j < 4; ++j) {
        float4 t;
        t.x = o4[j].x * factor; t.y = o4[j].y * factor;
        t.z = o4[j].z * factor; t.w = o4[j].w * factor;
        *(float4*)(so + wave * D_SZ + j * 256 + lane * 4) = t;
    }
    __syncthreads();

    // 256 threads: d = tid*4, sum the 4 wave regions.
    float4 a0 = *(float4*)(so + 0 * D_SZ + tid * 4);
    float4 a1 = *(float4*)(so + 1 * D_SZ + tid * 4);
    float4 a2 = *(float4*)(so + 2 * D_SZ + tid * 4);
    float4 a3 = *(float4*)(so + 3 * D_SZ + tid * 4);
    float4 sum;
    sum.x = a0.x + a1.x + a2.x + a3.x;
    sum.y = a0.y + a1.y + a2.y + a3.y;
    sum.z = a0.z + a1.z + a2.z + a3.z;
    sum.w = a0.w + a1.w + a2.w + a3.w;
    *(float4*)(o_ws + ((size_t)(b * PPB + c)) * D_SZ + tid * 4) = sum;
    if (tid == 0) { m_ws[b * PPB + c] = M; l_ws[b * PPB + c] = L; }
}

// ---------------- Kernel 3: combine partials ----------------
__global__ __launch_bounds__(256) void attn_reduce_kernel(
    const float* __restrict__ m_ws, const float* __restrict__ l_ws, const float* __restrict__ o_ws,
    float* __restrict__ out)
{
    const int b = blockIdx.x >> 2;        // 4 blocks per batch
    const int dchunk = blockIdx.x & 3;
    const int d = dchunk * 256 + threadIdx.x;

    float M = -3.0e38f;
    for (int p = 0; p < PPB; ++p) M = fmaxf(M, m_ws[b * PPB + p]);
    float L = 0.f;
    for (int p = 0; p < PPB; ++p) L += l_ws[b * PPB + p] * __expf(m_ws[b * PPB + p] - M);
    float acc = 0.f;
    for (int p = 0; p < PPB; ++p)
        acc += __expf(m_ws[b * PPB + p] - M) * o_ws[((size_t)(b * PPB + p)) * D_SZ + d];
    out[b * D_SZ + d] = acc / L;
}

extern "C" void kernel_launch(void* const* d_in, const int* in_sizes, int n_in,
                              void* d_out, int out_size, void* d_ws, size_t ws_size,
                              hipStream_t stream) {
    const float* x       = (const float*)d_in[0];
    const float* cache_k = (const float*)d_in[1];
    const float* cache_v = (const float*)d_in[2];
    const float* wq      = (const float*)d_in[3];
    const float* wk      = (const float*)d_in[4];
    const float* wv      = (const float*)d_in[5];
    float* out = (float*)d_out;
    float* ws  = (float*)d_ws;

    // Workspace layout (floats):
    float* q_ws  = ws;                          // 16*1024
    float* nk_ws = ws + 16384;                  // 16*1024
    float* nv_ws = ws + 32768;                  // 16*1024
    float* m_ws  = ws + 49152;                  // 16*64
    float* l_ws  = ws + 50176;                  // 16*64
    float* o_ws  = ws + 51200;                  // 16*64*1024 (16B-aligned: 51200 % 4 == 0)

    proj_kernel<<<768, 256, 0, stream>>>(x, wq, wk, wv, q_ws, nk_ws, nv_ws);
    attn_partial_kernel<<<B_SZ * PPB, 256, 0, stream>>>(cache_k, cache_v, q_ws, nk_ws, nv_ws,
                                                        m_ws, l_ws, o_ws);
    attn_reduce_kernel<<<B_SZ * 4, 256, 0, stream>>>(m_ws, l_ws, o_ws, out);
}